// Round 27
// baseline (152.794 us; speedup 1.0000x reference)
//
#include <hip/hip_runtime.h>

#define N_NODES 100000
#define F_IN    128
#define H_DIM   64
#define C_DIM   16
#define NBKT    391            // buckets of 256 nodes (dst>>8)
#define NTILE   6250           // 16-row gemm tiles
#define CHUNK   8192           // edges per bfill block
#define CAP     8960           // per-bucket csr capacity (lambda=8192, +8.5 sigma)
#define MAXCH   400            // >= nch = ceil(E/CHUNK) = 391

typedef __attribute__((ext_vector_type(8))) short bf16x8;   // 8 bf16 (4 VGPRs)
typedef __attribute__((ext_vector_type(4))) float f32x4;    // MFMA accum

// f32 -> bf16 round-to-nearest-even
__device__ __forceinline__ unsigned bfr(float f) {
    unsigned u = __float_as_uint(f);
    return (u + (((u >> 16) & 1u) + 0x7FFFu)) >> 16;
}
// fma-unpack: acc += d * bf16pair-vector (4 elems)
__device__ __forceinline__ void accbs(float4& a, uint2 u, float d) {
    a.x = fmaf(d, __uint_as_float(u.x << 16),         a.x);
    a.y = fmaf(d, __uint_as_float(u.x & 0xFFFF0000u), a.y);
    a.z = fmaf(d, __uint_as_float(u.y << 16),         a.z);
    a.w = fmaf(d, __uint_as_float(u.y & 0xFFFF0000u), a.w);
}
// plain unpack-add (gather2: g2b rows already dinv-prescaled)
__device__ __forceinline__ void accb(float4& a, uint2 u) {
    a.x += __uint_as_float(u.x << 16);
    a.y += __uint_as_float(u.x & 0xFFFF0000u);
    a.z += __uint_as_float(u.y << 16);
    a.w += __uint_as_float(u.y & 0xFFFF0000u);
}

// ---------- bfill v4: block-local sort + DENSE segment write (no RMW, no atomics)
__global__ __launch_bounds__(512) void k_bfill(const int2* __restrict__ edges,
                                               int* __restrict__ pairs_flat,
                                               int* __restrict__ cnts_g,
                                               int* __restrict__ lbase_g, int E) {
    __shared__ int2 sp[CHUNK];               // 64 KB block-sorted edge staging
    __shared__ int  cnt[NBKT];
    __shared__ int  lbase[NBKT];             // block-local exclusive base
    __shared__ int  scn[512];
    int t = threadIdx.x;
    for (int i = t; i < NBKT; i += 512) cnt[i] = 0;
    __syncthreads();
    int base = blockIdx.x * CHUNK;
    int m    = min(E - base, CHUNK);         // edges in this block
    int2 ed[16];                             // static idx via unroll (rule #20)
    int  rk[16];                             // rank within (block, bucket)
    #pragma unroll
    for (int i = 0; i < 16; ++i) {
        int e = i * 512 + t;
        if (e < m) {
            ed[i] = edges[base + e];
            rk[i] = atomicAdd(&cnt[ed[i].y >> 8], 1);
        }
    }
    __syncthreads();
    scn[t] = (t < NBKT) ? cnt[t] : 0;
    __syncthreads();
    #pragma unroll
    for (int off = 1; off < 512; off <<= 1) {
        int v = (t >= off) ? scn[t - off] : 0;
        __syncthreads();
        scn[t] += v;
        __syncthreads();
    }
    for (int b = t; b < NBKT; b += 512) {
        int c = cnt[b];
        int lb = scn[b] - c;                 // exclusive
        lbase[b] = lb;
        cnts_g [blockIdx.x * NBKT + b] = c;  // dense table writes (coalesced)
        lbase_g[blockIdx.x * NBKT + b] = lb;
    }
    __syncthreads();
    #pragma unroll
    for (int i = 0; i < 16; ++i) {
        int e = i * 512 + t;
        if (e < m) sp[lbase[ed[i].y >> 8] + rk[i]] = ed[i];
    }
    __syncthreads();
    #pragma unroll
    for (int i = 0; i < 16; ++i) {
        int idx = i * 512 + t;
        if (idx < m) {
            int2 p = sp[idx];
            pairs_flat[base + idx] = (p.x << 8) | (p.y & 255);
        }
    }
}

// ---------- FAT kernel, PARITY-INTERLEAVED roles ----------
// even blockIdx -> bnode bucket (blockIdx>>1); odd -> gemm tile group (blockIdx>>1).
// Interleave puts a 50/50 role mix in every dispatch window so each CU hosts
// one LDS/latency-heavy block beside one MFMA/stream-heavy block (m114 overlap).
struct SmemU {
    union {
        struct {                             // bnode role (~41 KB)
            int sc[CAP];
            int rcnt[MAXCH];
            int rlb[MAXCH];
            int cnt[256];
            int row[256];
            int wsum[4];
            int mtot;
        } b;
        short wt[64][132];                   // gemm role: W1^T bf16 (+4 pad)
    };
};

__global__ __launch_bounds__(1024) void k_fat(const int* __restrict__ pairs_flat,
                                              const int* __restrict__ cnts_g,
                                              const int* __restrict__ lbase_g,
                                              int* __restrict__ csr_src,
                                              int* __restrict__ node_base,
                                              int* __restrict__ node_cnt,
                                              float* __restrict__ dinv, int nch,
                                              const float* __restrict__ x,
                                              const float* __restrict__ W1,
                                              uint2* __restrict__ g1b) {
    __shared__ SmemU sm;
    int t = threadIdx.x;

    if ((blockIdx.x & 1) == 0) {
        // ================= bnode role: two-pass run-copy, no staging =================
        int b = blockIdx.x >> 1;             // bucket 0..390
        int lane = t & 63, wv = t >> 6;
        if (t < 256) sm.b.cnt[t] = 0;
        for (int i = t; i < nch; i += 1024) {            // column b of the tables
            sm.b.rcnt[i] = cnts_g [i * NBKT + b];
            sm.b.rlb[i]  = lbase_g[i * NBKT + b];
        }
        __syncthreads();
        // pass 1: hist (run-per-group reads, L2-hot)
        int grp = t >> 4, l16 = t & 15;
        for (int r = grp; r < nch; r += 64) {
            int c  = sm.b.rcnt[r];
            int rb = r * CHUNK + sm.b.rlb[r];
            for (int j = l16; j < c; j += 16)
                atomicAdd(&sm.b.cnt[pairs_flat[rb + j] & 255], 1);
        }
        __syncthreads();
        // node scan over 256 counts
        if (t < 256) {
            int c = sm.b.cnt[t];
            int v = c;
            #pragma unroll
            for (int off = 1; off < 64; off <<= 1) {
                int u = __shfl_up(v, off);
                if (lane >= off) v += u;
            }
            if (lane == 63) sm.b.wsum[wv] = v;
            __syncthreads();
            int woff = 0;
            #pragma unroll
            for (int w = 0; w < 4; ++w) woff += (w < wv) ? sm.b.wsum[w] : 0;
            int incl = v + woff;                         // inclusive over 256
            sm.b.row[t] = incl - c;                      // local exclusive base
            if (t == 255) sm.b.mtot = incl;
            int node = b * 256 + t;
            if (node < N_NODES) {
                node_base[node] = b * CAP + incl - c;
                node_cnt[node]  = c;
                dinv[node]      = rsqrtf((float)(c + 1));  // deg = cnt+1 (self loop)
            }
        } else {
            __syncthreads();                             // match scan barrier
        }
        __syncthreads();
        int m = min(sm.b.mtot, CAP);
        // pass 2: scatter to node order via LDS cursors (atomics proven free, R24)
        for (int r = grp; r < nch; r += 64) {
            int c  = sm.b.rcnt[r];
            int rb = r * CHUNK + sm.b.rlb[r];
            for (int j = l16; j < c; j += 16) {
                int p   = pairs_flat[rb + j];
                int pos = atomicAdd(&sm.b.row[p & 255], 1);
                if (pos < CAP) sm.b.sc[pos] = (p >> 8) & 0x1FFFF;
            }
        }
        __syncthreads();
        for (int e = t; e < m; e += 1024)
            csr_src[b * CAP + e] = sm.b.sc[e];           // coalesced copy-out
    } else {
        // ================= gemm1 role (MFMA bf16, UNSCALED): 16 waves x 16-row tiles
        {
            int n  = t & 63;
            int k0 = (t >> 6) * 8;                       // 16 groups x 8 k
            #pragma unroll
            for (int k = 0; k < 8; ++k)
                sm.wt[n][k0 + k] = (short)bfr(W1[(size_t)(k0 + k) * H_DIM + n]);
        }
        __syncthreads();

        int wave = t >> 6, lane = t & 63;
        int tile = (blockIdx.x >> 1) * 16 + wave;        // 391*16 = 6256 >= 6250
        bool valid = tile < NTILE;
        int row0 = (valid ? tile : 0) * 16;
        int l15  = lane & 15;
        int kg   = lane >> 4;                            // 0..3 (k-group of 8)
        const float* xrow = x + (size_t)(row0 + l15) * F_IN;

        f32x4 ac0 = {0.f,0.f,0.f,0.f}, ac1 = ac0, ac2 = ac0, ac3 = ac0;
        #pragma unroll
        for (int ks = 0; ks < 4; ++ks) {                 // K = 128 = 4 x 32
            int kb = ks * 32 + kg * 8;
            float4 p0 = *(const float4*)(xrow + kb);
            float4 p1 = *(const float4*)(xrow + kb + 4);
            bf16x8 a;
            a[0] = (short)bfr(p0.x); a[1] = (short)bfr(p0.y);
            a[2] = (short)bfr(p0.z); a[3] = (short)bfr(p0.w);
            a[4] = (short)bfr(p1.x); a[5] = (short)bfr(p1.y);
            a[6] = (short)bfr(p1.z); a[7] = (short)bfr(p1.w);
            bf16x8 b0 = *(const bf16x8*)&sm.wt[l15     ][kb];
            bf16x8 b1 = *(const bf16x8*)&sm.wt[l15 + 16][kb];
            bf16x8 b2 = *(const bf16x8*)&sm.wt[l15 + 32][kb];
            bf16x8 b3 = *(const bf16x8*)&sm.wt[l15 + 48][kb];
            ac0 = __builtin_amdgcn_mfma_f32_16x16x32_bf16(a, b0, ac0, 0, 0, 0);
            ac1 = __builtin_amdgcn_mfma_f32_16x16x32_bf16(a, b1, ac1, 0, 0, 0);
            ac2 = __builtin_amdgcn_mfma_f32_16x16x32_bf16(a, b2, ac2, 0, 0, 0);
            ac3 = __builtin_amdgcn_mfma_f32_16x16x32_bf16(a, b3, ac3, 0, 0, 0);
        }
        if (!valid) return;

        int rbase = row0 + kg * 4;                       // this lane's 4 output rows
        #pragma unroll
        for (int r = 0; r < 4; ++r) {
            size_t gro = (size_t)(rbase + r) * 16;
            #pragma unroll
            for (int ct = 0; ct < 4; ++ct) {
                float v = (ct == 0) ? ac0[r] : (ct == 1) ? ac1[r] :
                          (ct == 2) ? ac2[r] : ac3[r];
                float v1 = __shfl_down(v, 1);
                float v2 = __shfl_down(v, 2);
                float v3 = __shfl_down(v, 3);
                if ((l15 & 3) == 0) {
                    uint2 pk;
                    pk.x = bfr(v)  | (bfr(v1) << 16);
                    pk.y = bfr(v2) | (bfr(v3) << 16);
                    g1b[gro + ct * 4 + (l15 >> 2)] = pk;
                }
            }
        }
    }
}

// ---------- fused gather1 + bias + relu + GEMM2 (per-edge dinv staging) ----------
__global__ __launch_bounds__(256) void k_gather1(const int* __restrict__ csr_src,
                                                 const int* __restrict__ base,
                                                 const int* __restrict__ cnt,
                                                 const float* __restrict__ dinv,
                                                 const uint2* __restrict__ g1b,  // [N][16] UNSCALED
                                                 const float* __restrict__ b1,
                                                 const float* __restrict__ W2,   // [64][16]
                                                 uint2* __restrict__ g2b) {      // [N][4]
    __shared__ float  w2t[16 * 68];          // W2^T, rows padded to 68 floats
    __shared__ float4 ysh[4][68];            // per-wave y staging, 17-f4 group stride
    int tid = threadIdx.x;
    #pragma unroll
    for (int i = 0; i < 4; ++i) {
        int idx = i * 256 + tid;             // idx = f*16 + j
        w2t[(idx & 15) * 68 + (idx >> 4)] = W2[idx];
    }
    __syncthreads();

    int lane = tid & 63;
    int wv   = tid >> 6;                     // wave in block
    int grp  = lane >> 4;                    // 0..3
    int l16  = lane & 15;
    int g0   = lane & 48;                    // group base lane (absolute in wave)
    int node = ((blockIdx.x * 256 + tid) >> 6) * 4 + grp;   // exact: 25000 waves * 4
    int   b  = base[node];
    int   c  = cnt[node];
    float di = dinv[node];
    float4 acc = {0.f, 0.f, 0.f, 0.f};
    accbs(acc, g1b[(size_t)node * 16 + l16], di);      // self term dinv_i * h_i

    for (int k0 = 0; k0 < c; k0 += 16) {
        int k = k0 + l16;
        int   sidx = 0;
        float dn   = 0.f;
        if (k < c) { sidx = csr_src[b + k]; dn = dinv[sidx]; }  // staged idx + dinv
        int nj = min(16, c - k0);
        int j = 0;
        for (; j + 4 <= nj; j += 4) {
            int   s0 = __shfl(sidx, g0 + j + 0);
            int   s1 = __shfl(sidx, g0 + j + 1);
            int   s2 = __shfl(sidx, g0 + j + 2);
            int   s3 = __shfl(sidx, g0 + j + 3);
            float d0 = __shfl(dn,   g0 + j + 0);
            float d1 = __shfl(dn,   g0 + j + 1);
            float d2 = __shfl(dn,   g0 + j + 2);
            float d3 = __shfl(dn,   g0 + j + 3);
            uint2 u0 = g1b[(size_t)s0 * 16 + l16];     // 4 independent 128B rows
            uint2 u1 = g1b[(size_t)s1 * 16 + l16];
            uint2 u2 = g1b[(size_t)s2 * 16 + l16];
            uint2 u3 = g1b[(size_t)s3 * 16 + l16];
            accbs(acc, u0, d0); accbs(acc, u1, d1);
            accbs(acc, u2, d2); accbs(acc, u3, d3);
        }
        for (; j < nj; ++j) {
            accbs(acc, g1b[(size_t)__shfl(sidx, g0 + j) * 16 + l16],
                  __shfl(dn, g0 + j));
        }
    }

    // epilogue: y = di*relu(b1 + di*acc), transpose via LDS, y @ W2 -> g2b
    float4 bv = ((const float4*)b1)[l16];
    float4 y;
    y.x = fmaxf(fmaf(di, acc.x, bv.x), 0.f) * di;
    y.y = fmaxf(fmaf(di, acc.y, bv.y), 0.f) * di;
    y.z = fmaxf(fmaf(di, acc.z, bv.z), 0.f) * di;
    y.w = fmaxf(fmaf(di, acc.w, bv.w), 0.f) * di;
    ysh[wv][grp * 17 + l16] = y;             // wave-internal, DS-pipe ordered

    float o = 0.f;                           // this lane's output column j = l16
    #pragma unroll
    for (int f4 = 0; f4 < 16; ++f4) {
        float4 yv = ysh[wv][grp * 17 + f4];            // broadcast within group
        const float4* wr = (const float4*)&w2t[l16 * 68 + f4 * 4];
        float4 wv4 = *wr;
        o = fmaf(yv.x, wv4.x, o);
        o = fmaf(yv.y, wv4.y, o);
        o = fmaf(yv.z, wv4.z, o);
        o = fmaf(yv.w, wv4.w, o);
    }
    float o1 = __shfl_down(o, 1);
    float o2 = __shfl_down(o, 2);
    float o3 = __shfl_down(o, 3);
    if ((l16 & 3) == 0) {
        uint2 pk;
        pk.x = bfr(o)  | (bfr(o1) << 16);
        pk.y = bfr(o2) | (bfr(o3) << 16);
        g2b[(size_t)node * 4 + (l16 >> 2)] = pk;
    }
}

// ---------- gather layer 2: 4-lane group per node (16 nodes/wave), bf16 rows ----------
__global__ __launch_bounds__(256) void k_gather2(const int* __restrict__ csr_src,
                                                 const int* __restrict__ base,
                                                 const int* __restrict__ cnt,
                                                 const float* __restrict__ dinv,
                                                 const uint2* __restrict__ g2b,   // [N][4]
                                                 const float* __restrict__ b2,
                                                 float* __restrict__ out) {
    int tid  = threadIdx.x;
    int lane = tid & 63;
    int grp  = lane >> 2;                    // 0..15
    int l4   = lane & 3;
    int g0   = lane & 60;                    // group base lane
    int node = ((blockIdx.x * 256 + tid) >> 6) * 16 + grp;
    if (node >= N_NODES) return;
    int   b  = base[node];
    int   c  = cnt[node];
    float di = dinv[node];
    float4 acc = {0.f, 0.f, 0.f, 0.f};
    accb(acc, g2b[(size_t)node * 4 + l4]);             // self term (prescaled)

    for (int k0 = 0; k0 < c; k0 += 4) {
        int k = k0 + l4;
        int sidx = (k < c) ? csr_src[b + k] : 0;
        int nj = min(4, c - k0);
        if (nj == 4) {
            int s0 = __shfl(sidx, g0 + 0);
            int s1 = __shfl(sidx, g0 + 1);
            int s2 = __shfl(sidx, g0 + 2);
            int s3 = __shfl(sidx, g0 + 3);
            uint2 u0 = g2b[(size_t)s0 * 4 + l4];       // 4 independent 32B rows
            uint2 u1 = g2b[(size_t)s1 * 4 + l4];
            uint2 u2 = g2b[(size_t)s2 * 4 + l4];
            uint2 u3 = g2b[(size_t)s3 * 4 + l4];
            accb(acc, u0); accb(acc, u1); accb(acc, u2); accb(acc, u3);
        } else {
            for (int j = 0; j < nj; ++j)
                accb(acc, g2b[(size_t)__shfl(sidx, g0 + j) * 4 + l4]);
        }
    }
    float4 bv = ((const float4*)b2)[l4];
    float4 r  = { fmaf(di, acc.x, bv.x), fmaf(di, acc.y, bv.y),
                  fmaf(di, acc.z, bv.z), fmaf(di, acc.w, bv.w) };
    ((float4*)out)[(size_t)node * 4 + l4] = r;
}

extern "C" void kernel_launch(void* const* d_in, const int* in_sizes, int n_in,
                              void* d_out, int out_size, void* d_ws, size_t ws_size,
                              hipStream_t stream) {
    const float* x     = (const float*)d_in[0];
    const int*   edges = (const int*)d_in[1];              // int32 (harness converts)
    const float* W1    = (const float*)d_in[2];
    const float* b1    = (const float*)d_in[3];
    const float* W2    = (const float*)d_in[4];
    const float* b2    = (const float*)d_in[5];
    float*       out   = (float*)d_out;

    const int E   = in_sizes[1] / 2;                       // 3,200,000
    const int nch = (E + CHUNK - 1) / CHUNK;               // 391

    // workspace, ALL extents in ints (4B), regions strictly disjoint (~46 MB):
    //   pairs_flat: [0,           3,203,072)            12.8 MB  (nch*CHUNK)
    //   g1b:        [3,203,072,   6,403,072)            12.8 MB  (N*32 ints)
    //   g2b:        [6,403,072,   7,203,072)             3.2 MB  (N*8 ints)
    //   csr_src:    [7,203,136,  10,706,496)            14.0 MB  (NBKT*CAP)
    //   nbase/ncnt/dinv: +300,000; cnts_g/lbase_g: +305,762
    int*   pairs_flat = (int*)d_ws;
    uint2* g1b     = (uint2*)(pairs_flat + (size_t)nch * CHUNK);
    uint2* g2b     = (uint2*)((int*)g1b + (size_t)N_NODES * 32);
    int*   csr_src = (int*)g2b + (size_t)N_NODES * 8 + 64;
    int*   nbase   = csr_src + (size_t)NBKT * CAP;         // N
    int*   ncnt    = nbase + N_NODES;                      // N
    float* dinv    = (float*)(ncnt + N_NODES);             // N
    int*   cnts_g  = (int*)(dinv + N_NODES);               // nch*NBKT
    int*   lbase_g = cnts_g + (size_t)nch * NBKT;          // nch*NBKT

    // CSR build stage 1
    k_bfill <<<nch, 512, 0, stream>>>((const int2*)edges, pairs_flat,
                                      cnts_g, lbase_g, E);

    // FAT: parity-interleaved bnode/gemm1 roles (782 blocks = 2 x 391)
    k_fat <<<NBKT * 2, 1024, 0, stream>>>(pairs_flat, cnts_g, lbase_g, csr_src,
                                          nbase, ncnt, dinv, nch, x, W1, g1b);

    // fused: gather1 (per-edge dinv) + bias + relu + GEMM2 -> g2b
    k_gather1 <<<6250, 256, 0, stream>>>(csr_src, nbase, ncnt, dinv, g1b, b1, W2, g2b);

    // gather layer 2 -> out
    k_gather2 <<<1563, 256, 0, stream>>>(csr_src, nbase, ncnt, dinv, g2b, b2, out);
}

// Round 28
// 138.883 us; speedup vs baseline: 1.1002x; 1.1002x over previous
//
#include <hip/hip_runtime.h>

#define N_NODES 100000
#define F_IN    128
#define H_DIM   64
#define C_DIM   16
#define NBKT    391            // buckets of 256 nodes (dst>>8)
#define NTILE   6250           // 16-row gemm tiles
#define CHUNK   8192           // edges per bfill block
#define CAP     8960           // per-bucket csr capacity (lambda=8192, +8.5 sigma)
#define MAXCH   400            // >= nch = ceil(E/CHUNK) = 391

typedef __attribute__((ext_vector_type(8))) short bf16x8;   // 8 bf16 (4 VGPRs)
typedef __attribute__((ext_vector_type(4))) float f32x4;    // MFMA accum

// f32 -> bf16 round-to-nearest-even
__device__ __forceinline__ unsigned bfr(float f) {
    unsigned u = __float_as_uint(f);
    return (u + (((u >> 16) & 1u) + 0x7FFFu)) >> 16;
}
// fma-unpack: acc += d * bf16pair-vector (4 elems)
__device__ __forceinline__ void accbs(float4& a, uint2 u, float d) {
    a.x = fmaf(d, __uint_as_float(u.x << 16),         a.x);
    a.y = fmaf(d, __uint_as_float(u.x & 0xFFFF0000u), a.y);
    a.z = fmaf(d, __uint_as_float(u.y << 16),         a.z);
    a.w = fmaf(d, __uint_as_float(u.y & 0xFFFF0000u), a.w);
}
// plain unpack-add (gather2: g2b rows already dinv-prescaled)
__device__ __forceinline__ void accb(float4& a, uint2 u) {
    a.x += __uint_as_float(u.x << 16);
    a.y += __uint_as_float(u.x & 0xFFFF0000u);
    a.z += __uint_as_float(u.y << 16);
    a.w += __uint_as_float(u.y & 0xFFFF0000u);
}

// ---------- bfill v4: block-local sort + DENSE segment write (no RMW, no atomics)
__global__ __launch_bounds__(512) void k_bfill(const int2* __restrict__ edges,
                                               int* __restrict__ pairs_flat,
                                               int* __restrict__ cnts_g,
                                               int* __restrict__ lbase_g, int E) {
    __shared__ int2 sp[CHUNK];               // 64 KB block-sorted edge staging
    __shared__ int  cnt[NBKT];
    __shared__ int  lbase[NBKT];             // block-local exclusive base
    __shared__ int  scn[512];
    int t = threadIdx.x;
    for (int i = t; i < NBKT; i += 512) cnt[i] = 0;
    __syncthreads();
    int base = blockIdx.x * CHUNK;
    int m    = min(E - base, CHUNK);         // edges in this block
    int2 ed[16];                             // static idx via unroll (rule #20)
    int  rk[16];                             // rank within (block, bucket)
    #pragma unroll
    for (int i = 0; i < 16; ++i) {
        int e = i * 512 + t;
        if (e < m) {
            ed[i] = edges[base + e];
            rk[i] = atomicAdd(&cnt[ed[i].y >> 8], 1);
        }
    }
    __syncthreads();
    scn[t] = (t < NBKT) ? cnt[t] : 0;
    __syncthreads();
    #pragma unroll
    for (int off = 1; off < 512; off <<= 1) {
        int v = (t >= off) ? scn[t - off] : 0;
        __syncthreads();
        scn[t] += v;
        __syncthreads();
    }
    for (int b = t; b < NBKT; b += 512) {
        int c = cnt[b];
        int lb = scn[b] - c;                 // exclusive
        lbase[b] = lb;
        cnts_g [blockIdx.x * NBKT + b] = c;  // dense table writes (coalesced)
        lbase_g[blockIdx.x * NBKT + b] = lb;
    }
    __syncthreads();
    #pragma unroll
    for (int i = 0; i < 16; ++i) {
        int e = i * 512 + t;
        if (e < m) sp[lbase[ed[i].y >> 8] + rk[i]] = ed[i];
    }
    __syncthreads();
    #pragma unroll
    for (int i = 0; i < 16; ++i) {
        int idx = i * 512 + t;
        if (idx < m) {
            int2 p = sp[idx];
            pairs_flat[base + idx] = (p.x << 8) | (p.y & 255);
        }
    }
}

// ---------- FAT kernel: blocks [0,NBKT) = bnode; [NBKT, NBKT+391) = gemm1 ----------
// (R26 config: sequential role ranges — measured best 138.3 us. Parity interleave
// regressed: both roles contend on the VMEM/L2 path + LDS capacity, not on
// complementary pipes, so per-CU pairing serializes rather than overlaps.)
struct SmemU {
    union {
        struct {                             // bnode role (~41 KB)
            int sc[CAP];
            int rcnt[MAXCH];
            int rlb[MAXCH];
            int cnt[256];
            int row[256];
            int wsum[4];
            int mtot;
        } b;
        short wt[64][132];                   // gemm role: W1^T bf16 (+4 pad)
    };
};

__global__ __launch_bounds__(1024) void k_fat(const int* __restrict__ pairs_flat,
                                              const int* __restrict__ cnts_g,
                                              const int* __restrict__ lbase_g,
                                              int* __restrict__ csr_src,
                                              int* __restrict__ node_base,
                                              int* __restrict__ node_cnt,
                                              float* __restrict__ dinv, int nch,
                                              const float* __restrict__ x,
                                              const float* __restrict__ W1,
                                              uint2* __restrict__ g1b) {
    __shared__ SmemU sm;
    int t = threadIdx.x;

    if (blockIdx.x < NBKT) {
        // ================= bnode role: two-pass run-copy, no staging =================
        int b = blockIdx.x;
        int lane = t & 63, wv = t >> 6;
        if (t < 256) sm.b.cnt[t] = 0;
        for (int i = t; i < nch; i += 1024) {            // column b of the tables
            sm.b.rcnt[i] = cnts_g [i * NBKT + b];
            sm.b.rlb[i]  = lbase_g[i * NBKT + b];
        }
        __syncthreads();
        // pass 1: hist (run-per-group reads, L2-hot)
        int grp = t >> 4, l16 = t & 15;
        for (int r = grp; r < nch; r += 64) {
            int c  = sm.b.rcnt[r];
            int rb = r * CHUNK + sm.b.rlb[r];
            for (int j = l16; j < c; j += 16)
                atomicAdd(&sm.b.cnt[pairs_flat[rb + j] & 255], 1);
        }
        __syncthreads();
        // node scan over 256 counts
        if (t < 256) {
            int c = sm.b.cnt[t];
            int v = c;
            #pragma unroll
            for (int off = 1; off < 64; off <<= 1) {
                int u = __shfl_up(v, off);
                if (lane >= off) v += u;
            }
            if (lane == 63) sm.b.wsum[wv] = v;
            __syncthreads();
            int woff = 0;
            #pragma unroll
            for (int w = 0; w < 4; ++w) woff += (w < wv) ? sm.b.wsum[w] : 0;
            int incl = v + woff;                         // inclusive over 256
            sm.b.row[t] = incl - c;                      // local exclusive base
            if (t == 255) sm.b.mtot = incl;
            int node = b * 256 + t;
            if (node < N_NODES) {
                node_base[node] = b * CAP + incl - c;
                node_cnt[node]  = c;
                dinv[node]      = rsqrtf((float)(c + 1));  // deg = cnt+1 (self loop)
            }
        } else {
            __syncthreads();                             // match scan barrier
        }
        __syncthreads();
        int m = min(sm.b.mtot, CAP);
        // pass 2: scatter to node order via LDS cursors
        for (int r = grp; r < nch; r += 64) {
            int c  = sm.b.rcnt[r];
            int rb = r * CHUNK + sm.b.rlb[r];
            for (int j = l16; j < c; j += 16) {
                int p   = pairs_flat[rb + j];
                int pos = atomicAdd(&sm.b.row[p & 255], 1);
                if (pos < CAP) sm.b.sc[pos] = (p >> 8) & 0x1FFFF;
            }
        }
        __syncthreads();
        for (int e = t; e < m; e += 1024)
            csr_src[b * CAP + e] = sm.b.sc[e];           // coalesced copy-out
    } else {
        // ================= gemm1 role (MFMA bf16, UNSCALED): 16 waves x 16-row tiles
        {
            int n  = t & 63;
            int k0 = (t >> 6) * 8;                       // 16 groups x 8 k
            #pragma unroll
            for (int k = 0; k < 8; ++k)
                sm.wt[n][k0 + k] = (short)bfr(W1[(size_t)(k0 + k) * H_DIM + n]);
        }
        __syncthreads();

        int wave = t >> 6, lane = t & 63;
        int tile = (blockIdx.x - NBKT) * 16 + wave;      // 391*16 = 6256 >= 6250
        bool valid = tile < NTILE;
        int row0 = (valid ? tile : 0) * 16;
        int l15  = lane & 15;
        int kg   = lane >> 4;                            // 0..3 (k-group of 8)
        const float* xrow = x + (size_t)(row0 + l15) * F_IN;

        f32x4 ac0 = {0.f,0.f,0.f,0.f}, ac1 = ac0, ac2 = ac0, ac3 = ac0;
        #pragma unroll
        for (int ks = 0; ks < 4; ++ks) {                 // K = 128 = 4 x 32
            int kb = ks * 32 + kg * 8;
            float4 p0 = *(const float4*)(xrow + kb);
            float4 p1 = *(const float4*)(xrow + kb + 4);
            bf16x8 a;
            a[0] = (short)bfr(p0.x); a[1] = (short)bfr(p0.y);
            a[2] = (short)bfr(p0.z); a[3] = (short)bfr(p0.w);
            a[4] = (short)bfr(p1.x); a[5] = (short)bfr(p1.y);
            a[6] = (short)bfr(p1.z); a[7] = (short)bfr(p1.w);
            bf16x8 b0 = *(const bf16x8*)&sm.wt[l15     ][kb];
            bf16x8 b1 = *(const bf16x8*)&sm.wt[l15 + 16][kb];
            bf16x8 b2 = *(const bf16x8*)&sm.wt[l15 + 32][kb];
            bf16x8 b3 = *(const bf16x8*)&sm.wt[l15 + 48][kb];
            ac0 = __builtin_amdgcn_mfma_f32_16x16x32_bf16(a, b0, ac0, 0, 0, 0);
            ac1 = __builtin_amdgcn_mfma_f32_16x16x32_bf16(a, b1, ac1, 0, 0, 0);
            ac2 = __builtin_amdgcn_mfma_f32_16x16x32_bf16(a, b2, ac2, 0, 0, 0);
            ac3 = __builtin_amdgcn_mfma_f32_16x16x32_bf16(a, b3, ac3, 0, 0, 0);
        }
        if (!valid) return;

        int rbase = row0 + kg * 4;                       // this lane's 4 output rows
        #pragma unroll
        for (int r = 0; r < 4; ++r) {
            size_t gro = (size_t)(rbase + r) * 16;
            #pragma unroll
            for (int ct = 0; ct < 4; ++ct) {
                float v = (ct == 0) ? ac0[r] : (ct == 1) ? ac1[r] :
                          (ct == 2) ? ac2[r] : ac3[r];
                float v1 = __shfl_down(v, 1);
                float v2 = __shfl_down(v, 2);
                float v3 = __shfl_down(v, 3);
                if ((l15 & 3) == 0) {
                    uint2 pk;
                    pk.x = bfr(v)  | (bfr(v1) << 16);
                    pk.y = bfr(v2) | (bfr(v3) << 16);
                    g1b[gro + ct * 4 + (l15 >> 2)] = pk;
                }
            }
        }
    }
}

// ---------- fused gather1 + bias + relu + GEMM2 (per-edge dinv staging) ----------
__global__ __launch_bounds__(256) void k_gather1(const int* __restrict__ csr_src,
                                                 const int* __restrict__ base,
                                                 const int* __restrict__ cnt,
                                                 const float* __restrict__ dinv,
                                                 const uint2* __restrict__ g1b,  // [N][16] UNSCALED
                                                 const float* __restrict__ b1,
                                                 const float* __restrict__ W2,   // [64][16]
                                                 uint2* __restrict__ g2b) {      // [N][4]
    __shared__ float  w2t[16 * 68];          // W2^T, rows padded to 68 floats
    __shared__ float4 ysh[4][68];            // per-wave y staging, 17-f4 group stride
    int tid = threadIdx.x;
    #pragma unroll
    for (int i = 0; i < 4; ++i) {
        int idx = i * 256 + tid;             // idx = f*16 + j
        w2t[(idx & 15) * 68 + (idx >> 4)] = W2[idx];
    }
    __syncthreads();

    int lane = tid & 63;
    int wv   = tid >> 6;                     // wave in block
    int grp  = lane >> 4;                    // 0..3
    int l16  = lane & 15;
    int g0   = lane & 48;                    // group base lane (absolute in wave)
    int node = ((blockIdx.x * 256 + tid) >> 6) * 4 + grp;   // exact: 25000 waves * 4
    int   b  = base[node];
    int   c  = cnt[node];
    float di = dinv[node];
    float4 acc = {0.f, 0.f, 0.f, 0.f};
    accbs(acc, g1b[(size_t)node * 16 + l16], di);      // self term dinv_i * h_i

    for (int k0 = 0; k0 < c; k0 += 16) {
        int k = k0 + l16;
        int   sidx = 0;
        float dn   = 0.f;
        if (k < c) { sidx = csr_src[b + k]; dn = dinv[sidx]; }  // staged idx + dinv
        int nj = min(16, c - k0);
        int j = 0;
        for (; j + 4 <= nj; j += 4) {
            int   s0 = __shfl(sidx, g0 + j + 0);
            int   s1 = __shfl(sidx, g0 + j + 1);
            int   s2 = __shfl(sidx, g0 + j + 2);
            int   s3 = __shfl(sidx, g0 + j + 3);
            float d0 = __shfl(dn,   g0 + j + 0);
            float d1 = __shfl(dn,   g0 + j + 1);
            float d2 = __shfl(dn,   g0 + j + 2);
            float d3 = __shfl(dn,   g0 + j + 3);
            uint2 u0 = g1b[(size_t)s0 * 16 + l16];     // 4 independent 128B rows
            uint2 u1 = g1b[(size_t)s1 * 16 + l16];
            uint2 u2 = g1b[(size_t)s2 * 16 + l16];
            uint2 u3 = g1b[(size_t)s3 * 16 + l16];
            accbs(acc, u0, d0); accbs(acc, u1, d1);
            accbs(acc, u2, d2); accbs(acc, u3, d3);
        }
        for (; j < nj; ++j) {
            accbs(acc, g1b[(size_t)__shfl(sidx, g0 + j) * 16 + l16],
                  __shfl(dn, g0 + j));
        }
    }

    // epilogue: y = di*relu(b1 + di*acc), transpose via LDS, y @ W2 -> g2b
    float4 bv = ((const float4*)b1)[l16];
    float4 y;
    y.x = fmaxf(fmaf(di, acc.x, bv.x), 0.f) * di;
    y.y = fmaxf(fmaf(di, acc.y, bv.y), 0.f) * di;
    y.z = fmaxf(fmaf(di, acc.z, bv.z), 0.f) * di;
    y.w = fmaxf(fmaf(di, acc.w, bv.w), 0.f) * di;
    ysh[wv][grp * 17 + l16] = y;             // wave-internal, DS-pipe ordered

    float o = 0.f;                           // this lane's output column j = l16
    #pragma unroll
    for (int f4 = 0; f4 < 16; ++f4) {
        float4 yv = ysh[wv][grp * 17 + f4];            // broadcast within group
        const float4* wr = (const float4*)&w2t[l16 * 68 + f4 * 4];
        float4 wv4 = *wr;
        o = fmaf(yv.x, wv4.x, o);
        o = fmaf(yv.y, wv4.y, o);
        o = fmaf(yv.z, wv4.z, o);
        o = fmaf(yv.w, wv4.w, o);
    }
    float o1 = __shfl_down(o, 1);
    float o2 = __shfl_down(o, 2);
    float o3 = __shfl_down(o, 3);
    if ((l16 & 3) == 0) {
        uint2 pk;
        pk.x = bfr(o)  | (bfr(o1) << 16);
        pk.y = bfr(o2) | (bfr(o3) << 16);
        g2b[(size_t)node * 4 + (l16 >> 2)] = pk;
    }
}

// ---------- gather layer 2: 4-lane group per node (16 nodes/wave), bf16 rows ----------
__global__ __launch_bounds__(256) void k_gather2(const int* __restrict__ csr_src,
                                                 const int* __restrict__ base,
                                                 const int* __restrict__ cnt,
                                                 const float* __restrict__ dinv,
                                                 const uint2* __restrict__ g2b,   // [N][4]
                                                 const float* __restrict__ b2,
                                                 float* __restrict__ out) {
    int tid  = threadIdx.x;
    int lane = tid & 63;
    int grp  = lane >> 2;                    // 0..15
    int l4   = lane & 3;
    int g0   = lane & 60;                    // group base lane
    int node = ((blockIdx.x * 256 + tid) >> 6) * 16 + grp;
    if (node >= N_NODES) return;
    int   b  = base[node];
    int   c  = cnt[node];
    float di = dinv[node];
    float4 acc = {0.f, 0.f, 0.f, 0.f};
    accb(acc, g2b[(size_t)node * 4 + l4]);             // self term (prescaled)

    for (int k0 = 0; k0 < c; k0 += 4) {
        int k = k0 + l4;
        int sidx = (k < c) ? csr_src[b + k] : 0;
        int nj = min(4, c - k0);
        if (nj == 4) {
            int s0 = __shfl(sidx, g0 + 0);
            int s1 = __shfl(sidx, g0 + 1);
            int s2 = __shfl(sidx, g0 + 2);
            int s3 = __shfl(sidx, g0 + 3);
            uint2 u0 = g2b[(size_t)s0 * 4 + l4];       // 4 independent 32B rows
            uint2 u1 = g2b[(size_t)s1 * 4 + l4];
            uint2 u2 = g2b[(size_t)s2 * 4 + l4];
            uint2 u3 = g2b[(size_t)s3 * 4 + l4];
            accb(acc, u0); accb(acc, u1); accb(acc, u2); accb(acc, u3);
        } else {
            for (int j = 0; j < nj; ++j)
                accb(acc, g2b[(size_t)__shfl(sidx, g0 + j) * 4 + l4]);
        }
    }
    float4 bv = ((const float4*)b2)[l4];
    float4 r  = { fmaf(di, acc.x, bv.x), fmaf(di, acc.y, bv.y),
                  fmaf(di, acc.z, bv.z), fmaf(di, acc.w, bv.w) };
    ((float4*)out)[(size_t)node * 4 + l4] = r;
}

extern "C" void kernel_launch(void* const* d_in, const int* in_sizes, int n_in,
                              void* d_out, int out_size, void* d_ws, size_t ws_size,
                              hipStream_t stream) {
    const float* x     = (const float*)d_in[0];
    const int*   edges = (const int*)d_in[1];              // int32 (harness converts)
    const float* W1    = (const float*)d_in[2];
    const float* b1    = (const float*)d_in[3];
    const float* W2    = (const float*)d_in[4];
    const float* b2    = (const float*)d_in[5];
    float*       out   = (float*)d_out;

    const int E   = in_sizes[1] / 2;                       // 3,200,000
    const int nch = (E + CHUNK - 1) / CHUNK;               // 391

    // workspace, ALL extents in ints (4B), regions strictly disjoint (~46 MB):
    //   pairs_flat: [0,           3,203,072)            12.8 MB  (nch*CHUNK)
    //   g1b:        [3,203,072,   6,403,072)            12.8 MB  (N*32 ints)
    //   g2b:        [6,403,072,   7,203,072)             3.2 MB  (N*8 ints)
    //   csr_src:    [7,203,136,  10,706,496)            14.0 MB  (NBKT*CAP)
    //   nbase/ncnt/dinv: +300,000; cnts_g/lbase_g: +305,762
    int*   pairs_flat = (int*)d_ws;
    uint2* g1b     = (uint2*)(pairs_flat + (size_t)nch * CHUNK);
    uint2* g2b     = (uint2*)((int*)g1b + (size_t)N_NODES * 32);
    int*   csr_src = (int*)g2b + (size_t)N_NODES * 8 + 64;
    int*   nbase   = csr_src + (size_t)NBKT * CAP;         // N
    int*   ncnt    = nbase + N_NODES;                      // N
    float* dinv    = (float*)(ncnt + N_NODES);             // N
    int*   cnts_g  = (int*)(dinv + N_NODES);               // nch*NBKT
    int*   lbase_g = cnts_g + (size_t)nch * NBKT;          // nch*NBKT

    // CSR build stage 1
    k_bfill <<<nch, 512, 0, stream>>>((const int2*)edges, pairs_flat,
                                      cnts_g, lbase_g, E);

    // FAT: bnode (blocks 0..390) + gemm1 (blocks 391..781), sequential ranges
    k_fat <<<NBKT + 391, 1024, 0, stream>>>(pairs_flat, cnts_g, lbase_g, csr_src,
                                            nbase, ncnt, dinv, nch, x, W1, g1b);

    // fused: gather1 (per-edge dinv) + bias + relu + GEMM2 -> g2b
    k_gather1 <<<6250, 256, 0, stream>>>(csr_src, nbase, ncnt, dinv, g1b, b1, W2, g2b);

    // gather layer 2 -> out
    k_gather2 <<<1563, 256, 0, stream>>>(csr_src, nbase, ncnt, dinv, g2b, b2, out);
}